// Round 3
// baseline (404.480 us; speedup 1.0000x reference)
//
#include <hip/hip_runtime.h>
#include <hip/hip_bf16.h>

#define DIM 32
#define LOG_NPB 7
#define NPB 128              // nodes per bucket -> 16KB LDS accumulator tile
#define CAP 4096             // edge capacity per bucket (avg ~2046, Poisson std ~45)
#define NBINS 800            // >= ceil(100000/128)=782
#define EPB 4096             // edges per scatter block
#define EPT 16               // edges per thread in scatter (EPB/256)

// ---------------------------------------------------------------------------
// Kernel 1: out = x @ W2^T + b2 (fp32) ;  y = x @ W1^T (bf16)
// ---------------------------------------------------------------------------
__global__ __launch_bounds__(256) void fused_lin_kernel(
    const float* __restrict__ x,
    const float* __restrict__ W1,
    const float* __restrict__ W2,
    const float* __restrict__ b2,
    float* __restrict__ out,
    __hip_bfloat16* __restrict__ y,
    int n_nodes)
{
    __shared__ float W1s[DIM][DIM];  // W1s[k][c] = W1[c][k]
    __shared__ float W2s[DIM][DIM];
    __shared__ float b2s[DIM];
    __shared__ float xs[8][DIM];

    const int t = threadIdx.x;
    for (int i = t; i < DIM * DIM; i += 256) {
        int c = i >> 5, k = i & 31;
        W1s[k][c] = W1[i];
        W2s[k][c] = W2[i];
    }
    if (t < DIM) b2s[t] = b2[t];

    const int r = t >> 5;
    const int c = t & 31;
    const int ntiles = (n_nodes + 7) >> 3;

    for (int tile = blockIdx.x; tile < ntiles; tile += gridDim.x) {
        const int row = tile * 8 + r;
        __syncthreads();                       // covers weight staging + prev reads
        if (row < n_nodes) xs[r][c] = x[(long)row * DIM + c];
        __syncthreads();
        if (row < n_nodes) {
            float a2 = b2s[c];
            float a1 = 0.0f;
            #pragma unroll
            for (int k = 0; k < DIM; ++k) {
                float xv = xs[r][k];
                a2 += xv * W2s[k][c];
                a1 += xv * W1s[k][c];
            }
            out[(long)row * DIM + c] = a2;
            y[(long)row * DIM + c]   = __float2bfloat16(a1);
        }
    }
}

// ---------------------------------------------------------------------------
// cursor[b] = b*CAP
// ---------------------------------------------------------------------------
__global__ __launch_bounds__(256) void init_cursor_kernel(int* __restrict__ cursor, int nb)
{
    int i = blockIdx.x * 256 + threadIdx.x;
    if (i < nb) cursor[i] = i * CAP;
}

// ---------------------------------------------------------------------------
// Bucket scatter with block-level aggregation:
//   phase1: LDS histogram of this block's 4096 edges over 782 bins
//   phase2: one global fetch-add per non-empty bin -> block base
//   phase3: LDS rank -> write packed edge (src<<7 | dstLow) at base+rank
// ---------------------------------------------------------------------------
__global__ __launch_bounds__(256) void bucket_scatter_kernel(
    const int* __restrict__ src, const int* __restrict__ dst,
    int* __restrict__ cursor, unsigned* __restrict__ bedges, int nE)
{
    __shared__ int cnt[NBINS];
    __shared__ int base[NBINS];
    __shared__ int rank[NBINS];

    const int t = threadIdx.x;
    const long blockStart = (long)blockIdx.x * EPB;

    for (int i = t; i < NBINS; i += 256) { cnt[i] = 0; rank[i] = 0; }
    __syncthreads();

    int es[EPT], ed[EPT];
    #pragma unroll
    for (int i = 0; i < EPT; ++i) {
        long e = blockStart + i * 256 + t;
        if (e < nE) { es[i] = src[e]; ed[i] = dst[e]; }
        else        { es[i] = -1;     ed[i] = 0;      }
    }
    #pragma unroll
    for (int i = 0; i < EPT; ++i) {
        if (es[i] >= 0) atomicAdd(&cnt[ed[i] >> LOG_NPB], 1);
    }
    __syncthreads();

    for (int i = t; i < NBINS; i += 256) {
        int c = cnt[i];
        if (c > 0) base[i] = atomicAdd(&cursor[i], c);
    }
    __syncthreads();

    #pragma unroll
    for (int i = 0; i < EPT; ++i) {
        if (es[i] >= 0) {
            int b = ed[i] >> LOG_NPB;
            int r = atomicAdd(&rank[b], 1);
            int p = base[b] + r;
            if (p < (b + 1) * CAP)   // safety; never triggers for this input
                bedges[p] = ((unsigned)es[i] << LOG_NPB) | (unsigned)(ed[i] & (NPB - 1));
        }
    }
}

// ---------------------------------------------------------------------------
// One block per bucket: LDS fp32 accumulator tile [NPB][DIM], ds_add_f32,
// then a single coalesced out += tile.
// ---------------------------------------------------------------------------
__global__ __launch_bounds__(256) void bucket_accum_kernel(
    const int* __restrict__ cursor, const unsigned* __restrict__ bedges,
    const __hip_bfloat16* __restrict__ y,
    float* __restrict__ out, int n_nodes)
{
    __shared__ float acc[NPB * DIM];   // 16 KB

    const int b = blockIdx.x;
    const int t = threadIdx.x;

    for (int i = t; i < NPB * DIM; i += 256) acc[i] = 0.0f;
    __syncthreads();

    const int start = b * CAP;
    int end = cursor[b];                       // start + count
    if (end > start + CAP) end = start + CAP;

    const int el   = t >> 5;    // 0..7: edge slot within a round of 8
    const int dcol = t & 31;    // dim

    for (int e = start + el; e < end; e += 8) {
        unsigned ent = bedges[e];              // broadcast across 32 lanes
        int s  = (int)(ent >> LOG_NPB);
        int dl = (int)(ent & (NPB - 1));
        float v = __bfloat162float(y[(size_t)s * DIM + dcol]);  // 64B/edge coalesced
        atomicAdd(&acc[dl * DIM + dcol], v);   // bank = dcol: conflict-free
    }
    __syncthreads();

    const int nodeBase = b * NPB;
    for (int i = t; i < NPB * DIM; i += 256) {
        int node = nodeBase + (i >> 5);
        if (node < n_nodes) out[(size_t)node * DIM + (i & 31)] += acc[i];
    }
}

extern "C" void kernel_launch(void* const* d_in, const int* in_sizes, int n_in,
                              void* d_out, int out_size, void* d_ws, size_t ws_size,
                              hipStream_t stream) {
    const float* x  = (const float*)d_in[0];
    const float* W1 = (const float*)d_in[1];
    const float* W2 = (const float*)d_in[2];
    const float* b2 = (const float*)d_in[3];
    const int*   ei = (const int*)d_in[4];

    const int n_nodes = in_sizes[0] / DIM;   // 100000
    const int n_edges = in_sizes[4] / 2;     // 1,600,000
    const int* src = ei;
    const int* dst = ei + n_edges;
    float* out = (float*)d_out;

    const int nb = (n_nodes + NPB - 1) / NPB;    // 782

    // workspace layout
    char* basep = (char*)d_ws;
    size_t off = 0;
    auto alloc = [&](size_t bytes) {
        char* p = basep + off;
        off = (off + bytes + 255) & ~(size_t)255;
        return p;
    };
    __hip_bfloat16* y      = (__hip_bfloat16*)alloc((size_t)n_nodes * DIM * sizeof(__hip_bfloat16));
    int*            cursor = (int*)           alloc((size_t)nb * sizeof(int));
    unsigned*       bedges = (unsigned*)      alloc((size_t)nb * CAP * sizeof(unsigned));
    (void)ws_size;

    fused_lin_kernel<<<1024, 256, 0, stream>>>(x, W1, W2, b2, out, y, n_nodes);
    init_cursor_kernel<<<(nb + 255) / 256, 256, 0, stream>>>(cursor, nb);
    bucket_scatter_kernel<<<(n_edges + EPB - 1) / EPB, 256, 0, stream>>>(src, dst, cursor, bedges, n_edges);
    bucket_accum_kernel<<<nb, 256, 0, stream>>>(cursor, bedges, y, out, n_nodes);
}

// Round 4
// 398.769 us; speedup vs baseline: 1.0143x; 1.0143x over previous
//
#include <hip/hip_runtime.h>
#include <hip/hip_bf16.h>

#define DIM 32
#define LOG_NPB 7
#define NPB 128              // nodes per bucket -> 16KB LDS accumulator tile
#define CAP 4096             // edge capacity per bucket (avg ~2046, ~45 sigma headroom)
#define NBINS 800            // >= ceil(100000/128)=782
#define EPB 4096             // edges per scatter block
#define EPT 16               // edges per thread in scatter (EPB/256)
#define BATCH 8              // accum: edges in flight per 32-lane group

// ---------------------------------------------------------------------------
// Kernel 1: out = x @ W2^T + b2 (fp32) ;  y = x @ W1^T (bf16)
// ---------------------------------------------------------------------------
__global__ __launch_bounds__(256) void fused_lin_kernel(
    const float* __restrict__ x,
    const float* __restrict__ W1,
    const float* __restrict__ W2,
    const float* __restrict__ b2,
    float* __restrict__ out,
    __hip_bfloat16* __restrict__ y,
    int n_nodes)
{
    __shared__ float W1s[DIM][DIM];  // W1s[k][c] = W1[c][k]
    __shared__ float W2s[DIM][DIM];
    __shared__ float b2s[DIM];
    __shared__ float xs[8][DIM];

    const int t = threadIdx.x;
    for (int i = t; i < DIM * DIM; i += 256) {
        int c = i >> 5, k = i & 31;
        W1s[k][c] = W1[i];
        W2s[k][c] = W2[i];
    }
    if (t < DIM) b2s[t] = b2[t];

    const int r = t >> 5;
    const int c = t & 31;
    const int ntiles = (n_nodes + 7) >> 3;

    for (int tile = blockIdx.x; tile < ntiles; tile += gridDim.x) {
        const int row = tile * 8 + r;
        __syncthreads();
        if (row < n_nodes) xs[r][c] = x[(long)row * DIM + c];
        __syncthreads();
        if (row < n_nodes) {
            float a2 = b2s[c];
            float a1 = 0.0f;
            #pragma unroll
            for (int k = 0; k < DIM; ++k) {
                float xv = xs[r][k];
                a2 += xv * W2s[k][c];
                a1 += xv * W1s[k][c];
            }
            out[(long)row * DIM + c] = a2;
            y[(long)row * DIM + c]   = __float2bfloat16(a1);
        }
    }
}

__global__ __launch_bounds__(256) void init_cursor_kernel(int* __restrict__ cursor, int nb)
{
    int i = blockIdx.x * 256 + threadIdx.x;
    if (i < nb) cursor[i] = i * CAP;
}

// ---------------------------------------------------------------------------
// Bucket scatter with block-level aggregation (unchanged from round 3).
// ---------------------------------------------------------------------------
__global__ __launch_bounds__(256) void bucket_scatter_kernel(
    const int* __restrict__ src, const int* __restrict__ dst,
    int* __restrict__ cursor, unsigned* __restrict__ bedges, int nE)
{
    __shared__ int cnt[NBINS];
    __shared__ int base[NBINS];
    __shared__ int rank[NBINS];

    const int t = threadIdx.x;
    const long blockStart = (long)blockIdx.x * EPB;

    for (int i = t; i < NBINS; i += 256) { cnt[i] = 0; rank[i] = 0; }
    __syncthreads();

    int es[EPT], ed[EPT];
    #pragma unroll
    for (int i = 0; i < EPT; ++i) {
        long e = blockStart + i * 256 + t;
        if (e < nE) { es[i] = src[e]; ed[i] = dst[e]; }
        else        { es[i] = -1;     ed[i] = 0;      }
    }
    #pragma unroll
    for (int i = 0; i < EPT; ++i) {
        if (es[i] >= 0) atomicAdd(&cnt[ed[i] >> LOG_NPB], 1);
    }
    __syncthreads();

    for (int i = t; i < NBINS; i += 256) {
        int c = cnt[i];
        if (c > 0) base[i] = atomicAdd(&cursor[i], c);
    }
    __syncthreads();

    #pragma unroll
    for (int i = 0; i < EPT; ++i) {
        if (es[i] >= 0) {
            int b = ed[i] >> LOG_NPB;
            int r = atomicAdd(&rank[b], 1);
            int p = base[b] + r;
            if (p < (b + 1) * CAP)
                bedges[p] = ((unsigned)es[i] << LOG_NPB) | (unsigned)(ed[i] & (NPB - 1));
        }
    }
}

// ---------------------------------------------------------------------------
// One block per bucket, ILP-batched: each 32-lane group keeps BATCH=8
// independent y-gathers in flight per iteration.
// ---------------------------------------------------------------------------
__global__ __launch_bounds__(256) void bucket_accum_kernel(
    const int* __restrict__ cursor, const unsigned* __restrict__ bedges,
    const __hip_bfloat16* __restrict__ y,
    float* __restrict__ out, int n_nodes)
{
    __shared__ float acc[NPB * DIM];   // 16 KB

    const int b = blockIdx.x;
    const int t = threadIdx.x;

    for (int i = t; i < NPB * DIM; i += 256) acc[i] = 0.0f;
    __syncthreads();

    const int start = b * CAP;
    int end = cursor[b];
    if (end > start + CAP) end = start + CAP;

    const int el   = t >> 5;    // group 0..7
    const int dcol = t & 31;    // dim

    // group el owns chunks [start + el*BATCH + k*8*BATCH, +BATCH)
    for (int ebase = start + el * BATCH; ebase < end; ebase += 8 * BATCH) {
        const int n = min(BATCH, end - ebase);
        unsigned ent[BATCH];
        float    v[BATCH];
        #pragma unroll
        for (int i = 0; i < BATCH; ++i)
            ent[i] = (i < n) ? bedges[ebase + i] : 0u;     // contiguous, independent
        #pragma unroll
        for (int i = 0; i < BATCH; ++i)
            if (i < n) v[i] = __bfloat162float(y[(size_t)(ent[i] >> LOG_NPB) * DIM + dcol]);
        #pragma unroll
        for (int i = 0; i < BATCH; ++i)
            if (i < n) atomicAdd(&acc[(ent[i] & (NPB - 1)) * DIM + dcol], v[i]);
    }
    __syncthreads();

    const int nodeBase = b * NPB;
    for (int i = t; i < NPB * DIM; i += 256) {
        int node = nodeBase + (i >> 5);
        if (node < n_nodes) out[(size_t)node * DIM + (i & 31)] += acc[i];
    }
}

extern "C" void kernel_launch(void* const* d_in, const int* in_sizes, int n_in,
                              void* d_out, int out_size, void* d_ws, size_t ws_size,
                              hipStream_t stream) {
    const float* x  = (const float*)d_in[0];
    const float* W1 = (const float*)d_in[1];
    const float* W2 = (const float*)d_in[2];
    const float* b2 = (const float*)d_in[3];
    const int*   ei = (const int*)d_in[4];

    const int n_nodes = in_sizes[0] / DIM;   // 100000
    const int n_edges = in_sizes[4] / 2;     // 1,600,000
    const int* src = ei;
    const int* dst = ei + n_edges;
    float* out = (float*)d_out;

    const int nb = (n_nodes + NPB - 1) / NPB;    // 782

    char* basep = (char*)d_ws;
    size_t off = 0;
    auto alloc = [&](size_t bytes) {
        char* p = basep + off;
        off = (off + bytes + 255) & ~(size_t)255;
        return p;
    };
    __hip_bfloat16* y      = (__hip_bfloat16*)alloc((size_t)n_nodes * DIM * sizeof(__hip_bfloat16));
    int*            cursor = (int*)           alloc((size_t)nb * sizeof(int));
    unsigned*       bedges = (unsigned*)      alloc((size_t)nb * CAP * sizeof(unsigned));
    (void)ws_size;

    fused_lin_kernel<<<1024, 256, 0, stream>>>(x, W1, W2, b2, out, y, n_nodes);
    init_cursor_kernel<<<(nb + 255) / 256, 256, 0, stream>>>(cursor, nb);
    bucket_scatter_kernel<<<(n_edges + EPB - 1) / EPB, 256, 0, stream>>>(src, dst, cursor, bedges, n_edges);
    bucket_accum_kernel<<<nb, 256, 0, stream>>>(cursor, bedges, y, out, n_nodes);
}

// Round 5
// 105.171 us; speedup vs baseline: 3.8459x; 3.7916x over previous
//
#include <hip/hip_runtime.h>
#include <hip/hip_bf16.h>

#define DIM 32
#define LOG_NPB 7
#define NPB 128              // nodes per bucket
#define CAP 4096             // edge capacity per bucket (avg ~2046)
#define NBINS 800            // >= ceil(100000/128)=782
#define EPB 4096             // edges per scatter block
#define EPT 16               // edges per thread in scatter (EPB/256)

// ---------------------------------------------------------------------------
// Kernel 1: out = x @ W2^T + b2 (fp32) ;  y = x @ W1^T (bf16)
// ---------------------------------------------------------------------------
__global__ __launch_bounds__(256) void fused_lin_kernel(
    const float* __restrict__ x,
    const float* __restrict__ W1,
    const float* __restrict__ W2,
    const float* __restrict__ b2,
    float* __restrict__ out,
    __hip_bfloat16* __restrict__ y,
    int n_nodes)
{
    __shared__ float W1s[DIM][DIM];
    __shared__ float W2s[DIM][DIM];
    __shared__ float b2s[DIM];
    __shared__ float xs[8][DIM];

    const int t = threadIdx.x;
    for (int i = t; i < DIM * DIM; i += 256) {
        int c = i >> 5, k = i & 31;
        W1s[k][c] = W1[i];
        W2s[k][c] = W2[i];
    }
    if (t < DIM) b2s[t] = b2[t];

    const int r = t >> 5;
    const int c = t & 31;
    const int ntiles = (n_nodes + 7) >> 3;

    for (int tile = blockIdx.x; tile < ntiles; tile += gridDim.x) {
        const int row = tile * 8 + r;
        __syncthreads();
        if (row < n_nodes) xs[r][c] = x[(long)row * DIM + c];
        __syncthreads();
        if (row < n_nodes) {
            float a2 = b2s[c];
            float a1 = 0.0f;
            #pragma unroll
            for (int k = 0; k < DIM; ++k) {
                float xv = xs[r][k];
                a2 += xv * W2s[k][c];
                a1 += xv * W1s[k][c];
            }
            out[(long)row * DIM + c] = a2;
            y[(long)row * DIM + c]   = __float2bfloat16(a1);
        }
    }
}

__global__ __launch_bounds__(256) void init_cursor_kernel(int* __restrict__ cursor, int nb)
{
    int i = blockIdx.x * 256 + threadIdx.x;
    if (i < nb) cursor[i] = i * CAP;
}

// ---------------------------------------------------------------------------
// Pass 1: bucket scatter with block-level LDS aggregation (782 buckets).
// ---------------------------------------------------------------------------
__global__ __launch_bounds__(256) void bucket_scatter_kernel(
    const int* __restrict__ src, const int* __restrict__ dst,
    int* __restrict__ cursor, unsigned* __restrict__ bedges, int nE)
{
    __shared__ int cnt[NBINS];
    __shared__ int base[NBINS];
    __shared__ int rank[NBINS];

    const int t = threadIdx.x;
    const long blockStart = (long)blockIdx.x * EPB;

    for (int i = t; i < NBINS; i += 256) { cnt[i] = 0; rank[i] = 0; }
    __syncthreads();

    int es[EPT], ed[EPT];
    #pragma unroll
    for (int i = 0; i < EPT; ++i) {
        long e = blockStart + i * 256 + t;
        if (e < nE) { es[i] = src[e]; ed[i] = dst[e]; }
        else        { es[i] = -1;     ed[i] = 0;      }
    }
    #pragma unroll
    for (int i = 0; i < EPT; ++i) {
        if (es[i] >= 0) atomicAdd(&cnt[ed[i] >> LOG_NPB], 1);
    }
    __syncthreads();

    for (int i = t; i < NBINS; i += 256) {
        int c = cnt[i];
        if (c > 0) base[i] = atomicAdd(&cursor[i], c);
    }
    __syncthreads();

    #pragma unroll
    for (int i = 0; i < EPT; ++i) {
        if (es[i] >= 0) {
            int b = ed[i] >> LOG_NPB;
            int r = atomicAdd(&rank[b], 1);
            int p = base[b] + r;
            if (p < (b + 1) * CAP)
                bedges[p] = ((unsigned)es[i] << LOG_NPB) | (unsigned)(ed[i] & (NPB - 1));
        }
    }
}

// ---------------------------------------------------------------------------
// Pass 2: in-bucket sort to node granularity. One block per bucket.
// Rewrites bedges[start..start+n) as src-ids sorted by local dst,
// and emits row_start / row_cnt per node.
// ---------------------------------------------------------------------------
__global__ __launch_bounds__(256) void bucket_sort_kernel(
    const int* __restrict__ cursor, unsigned* __restrict__ bedges,
    int* __restrict__ row_start, int* __restrict__ row_cnt, int n_nodes)
{
    __shared__ unsigned ent[CAP];     // 16 KB
    __shared__ int cnt[NPB];
    __shared__ int ex[NPB];           // exclusive bin starts
    __shared__ int cur[NPB];

    const int b = blockIdx.x;
    const int t = threadIdx.x;
    const int start = b * CAP;
    int n = cursor[b] - start;
    if (n > CAP) n = CAP;
    if (n < 0) n = 0;

    if (t < NPB) { cnt[t] = 0; cur[t] = 0; }
    __syncthreads();

    for (int i = t; i < n; i += 256) {
        unsigned e = bedges[start + i];
        ent[i] = e;
        atomicAdd(&cnt[e & (NPB - 1)], 1);
    }
    __syncthreads();

    // inclusive scan over 128 bins -> ex (exclusive)
    if (t < NPB) ex[t] = cnt[t];
    __syncthreads();
    for (int off = 1; off < NPB; off <<= 1) {
        int add = 0;
        if (t < NPB && t >= off) add = ex[t - off];
        __syncthreads();
        if (t < NPB) ex[t] += add;
        __syncthreads();
    }
    if (t < NPB) ex[t] -= cnt[t];
    __syncthreads();

    // rank + sorted write-back (store plain src id)
    for (int i = t; i < n; i += 256) {
        unsigned e = ent[i];
        int bin = (int)(e & (NPB - 1));
        int r = atomicAdd(&cur[bin], 1);
        bedges[start + ex[bin] + r] = e >> LOG_NPB;
    }

    if (t < NPB) {
        int node = b * NPB + t;
        if (node < n_nodes) {
            row_start[node] = start + ex[t];
            row_cnt[node]   = cnt[t];
        }
    }
}

// ---------------------------------------------------------------------------
// Pass 3: gather. One wave per node; half-waves (el=0/1) each keep 8
// clamped (always-valid) loads in flight. No atomics, out written once.
// ---------------------------------------------------------------------------
__global__ __launch_bounds__(256) void gather_kernel(
    const int* __restrict__ row_start, const int* __restrict__ row_cnt,
    const unsigned* __restrict__ bedges, const __hip_bfloat16* __restrict__ y,
    float* __restrict__ out, int n_nodes)
{
    const int wid  = (blockIdx.x * 256 + threadIdx.x) >> 6;   // node id
    const int lane = threadIdx.x & 63;
    if (wid >= n_nodes) return;

    const int start = row_start[wid];
    const int cnt   = row_cnt[wid];
    const int end   = start + cnt;
    const int el = lane >> 5;    // half-wave: 0 or 1
    const int d  = lane & 31;    // dim

    float acc = 0.0f;
    for (int base = start + el * 8; base < end; base += 16) {
        int srcs[8];
        #pragma unroll
        for (int i = 0; i < 8; ++i) {
            int idx = base + i;
            srcs[i] = (int)bedges[idx < end ? idx : (end - 1)];   // clamped, unguarded
        }
        float v[8];
        #pragma unroll
        for (int i = 0; i < 8; ++i)
            v[i] = __bfloat162float(y[(size_t)srcs[i] * DIM + d]);
        #pragma unroll
        for (int i = 0; i < 8; ++i)
            acc += (base + i < end) ? v[i] : 0.0f;
    }
    acc += __shfl_xor(acc, 32);
    if (el == 0) out[(size_t)wid * DIM + d] += acc;
}

extern "C" void kernel_launch(void* const* d_in, const int* in_sizes, int n_in,
                              void* d_out, int out_size, void* d_ws, size_t ws_size,
                              hipStream_t stream) {
    const float* x  = (const float*)d_in[0];
    const float* W1 = (const float*)d_in[1];
    const float* W2 = (const float*)d_in[2];
    const float* b2 = (const float*)d_in[3];
    const int*   ei = (const int*)d_in[4];

    const int n_nodes = in_sizes[0] / DIM;   // 100000
    const int n_edges = in_sizes[4] / 2;     // 1,600,000
    const int* src = ei;
    const int* dst = ei + n_edges;
    float* out = (float*)d_out;

    const int nb = (n_nodes + NPB - 1) / NPB;    // 782

    char* basep = (char*)d_ws;
    size_t off = 0;
    auto alloc = [&](size_t bytes) {
        char* p = basep + off;
        off = (off + bytes + 255) & ~(size_t)255;
        return p;
    };
    __hip_bfloat16* y        = (__hip_bfloat16*)alloc((size_t)n_nodes * DIM * sizeof(__hip_bfloat16));
    int*            cursor   = (int*)           alloc((size_t)nb * sizeof(int));
    unsigned*       bedges   = (unsigned*)      alloc((size_t)nb * CAP * sizeof(unsigned));
    int*            rowst    = (int*)           alloc((size_t)n_nodes * sizeof(int));
    int*            rowcnt   = (int*)           alloc((size_t)n_nodes * sizeof(int));
    (void)ws_size;

    fused_lin_kernel<<<1024, 256, 0, stream>>>(x, W1, W2, b2, out, y, n_nodes);
    init_cursor_kernel<<<(nb + 255) / 256, 256, 0, stream>>>(cursor, nb);
    bucket_scatter_kernel<<<(n_edges + EPB - 1) / EPB, 256, 0, stream>>>(src, dst, cursor, bedges, n_edges);
    bucket_sort_kernel<<<nb, 256, 0, stream>>>(cursor, bedges, rowst, rowcnt, n_nodes);
    gather_kernel<<<(n_nodes * 64 + 255) / 256, 256, 0, stream>>>(rowst, rowcnt, bedges, y, out, n_nodes);
}